// Round 5
// baseline (273.153 us; speedup 1.0000x reference)
//
#include <hip/hip_runtime.h>
#include <hip/hip_bf16.h>

// Problem constants
#define BB 4
#define SS 4096
#define DM 1024
#define HH 16
#define PP 32
#define RR 8
#define DD 64
#define NTOK (BB*SS)          // 16384 tokens
#define MM NTOK               // GEMM M
#define NN DM                 // GEMM N
#define KK DM                 // GEMM K

typedef __attribute__((ext_vector_type(8))) short short8;
typedef __attribute__((ext_vector_type(4))) float floatx4;

static __device__ inline short f2bf(float f) {
    union { __hip_bfloat16 b; short s; } u; u.b = __float2bfloat16(f); return u.s;
}
static __device__ inline short8 pack8(float4 lo, float4 hi) {
    short8 r;
    r[0] = f2bf(lo.x); r[1] = f2bf(lo.y); r[2] = f2bf(lo.z); r[3] = f2bf(lo.w);
    r[4] = f2bf(hi.x); r[5] = f2bf(hi.y); r[6] = f2bf(hi.z); r[7] = f2bf(hi.w);
    return r;
}

// Fast RNE bf16 pack: identical bits to __float2bfloat16 for finite inputs.
static __device__ inline unsigned bfr(float f) {
    unsigned u = __float_as_uint(f);
    return u + 0x7fffu + ((u >> 16) & 1u);
}
static __device__ inline int pk2(float a, float b) {  // low16=bf(a), high16=bf(b)
    return __builtin_amdgcn_perm(bfr(b), bfr(a), 0x07060302);
}
static __device__ inline short8 pk8(float4 lo, float4 hi) {
    union { short8 s; int i[4]; } r;
    r.i[0] = pk2(lo.x, lo.y); r.i[1] = pk2(lo.z, lo.w);
    r.i[2] = pk2(hi.x, hi.y); r.i[3] = pk2(hi.z, hi.w);
    return r.s;
}

// ---------------------------------------------------------------------------
// Kernel 1: W_out (f32 [k][n]) -> bf16 MFMA B-fragment order (unchanged).
// ---------------------------------------------------------------------------
__global__ __launch_bounds__(256) void convert_w(const float* __restrict__ Wo,
                                                 __hip_bfloat16* __restrict__ wsw) {
    int tid = blockIdx.x * 256 + threadIdx.x;     // 0 .. 131071
    int l = tid & 63;
    int kblk = (tid >> 6) & 31;
    int ntile = tid >> 11;
    int col = ntile * 16 + (l & 15);
    int krow = kblk * 32 + (l >> 4) * 8;
#pragma unroll
    for (int j = 0; j < 8; ++j) {
        wsw[(size_t)tid * 8 + j] = __float2bfloat16(Wo[(size_t)(krow + j) * NN + col]);
    }
}

// ---------------------------------------------------------------------------
// Kernel 1b: K_state / V_state -> MFMA A-frag layouts (unchanged from R3).
// ---------------------------------------------------------------------------
__global__ __launch_bounds__(256) void convert_kv(const float* __restrict__ Kst,
                                                  const float* __restrict__ Vst,
                                                  __hip_bfloat16* __restrict__ kfrag,
                                                  __hip_bfloat16* __restrict__ vfrag) {
    int tid = blockIdx.x * 256 + threadIdx.x;     // 0..65535
    int arr = tid >> 15;
    int idx = tid & 32767;
    int h = idx >> 11, blk = (idx >> 6) & 31, fl = idx & 63;
    int fm = fl & 15, fk = fl >> 4;
    short8 val;
    short* dst;
    if (arr == 0) {
        int mt = blk >> 1, kb = blk & 1;
        int pr = mt * 16 + fm, d0 = kb * 32 + fk * 8;
        const float* src = Kst + ((size_t)h * 256 + pr) * 64 + d0;
        float4 lo = *(const float4*)src, hi = *(const float4*)(src + 4);
        val = pack8(lo, hi);
        dst = (short*)kfrag + (size_t)idx * 8;
    } else {
        int mt = blk >> 3, kb = blk & 7;
        int d = mt * 16 + fm, pr0 = kb * 32 + fk * 8;
        const float* src = Vst + ((size_t)h * 256 + pr0) * 64 + d;
#pragma unroll
        for (int j = 0; j < 8; ++j) val[j] = f2bf(src[j * 64]);
        dst = (short*)vfrag + (size_t)idx * 8;
    }
    *(short8*)dst = val;
}

// ---------------------------------------------------------------------------
// Kernel 2a (router): exact fp32 logits + top-k + gates -> global fp32.
// Block = 64 tokens x 1 head. Logits FMA chain and top-k code are verbatim
// from the verified R4 kernel (bitwise-identical selection). gates_g aliases
// d_out (consumed by attn_v5 before gemm overwrites d_out).
// ---------------------------------------------------------------------------
__global__ __launch_bounds__(256, 4) void router(const float* __restrict__ x,
                                                 const float* __restrict__ Wr,
                                                 const int* __restrict__ kp,
                                                 float* __restrict__ gates_g) {
    __shared__ __align__(16) float xs[64][68];
    __shared__ __align__(16) float Lg[64][36];

    const int lane = threadIdx.x & 63;
    const int w = threadIdx.x >> 6;
    const int t0 = blockIdx.x * 64;
    const int h = blockIdx.y;

    // ---- stage x tile [64 t x 64 d] into LDS ----
    {
        int row = threadIdx.x >> 2, q = threadIdx.x & 3;
        const float4* src = (const float4*)(x + (size_t)(t0 + row) * DM + h * 64 + q * 16);
        float4 v0 = src[0], v1 = src[1], v2 = src[2], v3 = src[3];
        float4* dst = (float4*)&xs[row][q * 16];
        dst[0] = v0; dst[1] = v1; dst[2] = v2; dst[3] = v3;
    }

    // ---- preload router weights (exact R1 pattern) ----
    const int p = lane & 31, dh = lane >> 5;
    float wreg[32];
    {
        const float* wrp = Wr + (size_t)h * (DD * PP) + dh * 32 * PP + p;
#pragma unroll
        for (int dd = 0; dd < 32; ++dd) wreg[dd] = wrp[dd * PP];
    }
    const int kkv = kp[0];

    __syncthreads();

    // ---- logits: arithmetic chain bitwise-identical to R1..R4 ----
    for (int it = 0; it < 16; ++it) {
        int t = w * 16 + it;
        float xf[32];
#pragma unroll
        for (int j = 0; j < 8; ++j) {
            float4 tq = *(const float4*)&xs[t][dh * 32 + 4 * j];
            xf[4 * j] = tq.x; xf[4 * j + 1] = tq.y; xf[4 * j + 2] = tq.z; xf[4 * j + 3] = tq.w;
        }
        float lg = 0.f;
#pragma unroll
        for (int dd = 0; dd < 32; ++dd) lg += xf[dd] * wreg[dd];
        lg += __shfl_xor(lg, 32);
        if (lane < 32) Lg[t][lane] = lg;
    }
    __syncthreads();

    // ---- top-k + gates, in-register per token (lanes 0..15), verbatim R4 ----
    if (lane < 16) {
        int t = w * 16 + lane;
        float lgr[32];
        const float4* lrow = (const float4*)&Lg[t][0];
#pragma unroll
        for (int c = 0; c < 8; ++c) {
            float4 q4 = lrow[c];
            lgr[4 * c] = q4.x; lgr[4 * c + 1] = q4.y; lgr[4 * c + 2] = q4.z; lgr[4 * c + 3] = q4.w;
        }
        float a1 = -INFINITY, b2 = -INFINITY, c3 = -INFINITY, d4 = -INFINITY;
#pragma unroll
        for (int pp = 0; pp < 32; ++pp) {
            float v = lgr[pp];
            float na = fmaxf(a1, v); v = fminf(a1, v); a1 = na;
            float nb = fmaxf(b2, v); v = fminf(b2, v); b2 = nb;
            float nc = fmaxf(c3, v); v = fminf(c3, v); c3 = nc;
            d4 = fmaxf(d4, v);
        }
        float thresh = (kkv >= 4) ? d4 : (kkv == 3 ? c3 : (kkv == 2 ? b2 : a1));
        float den = 0.f;
        float garr[32];
#pragma unroll
        for (int pp = 0; pp < 32; ++pp) {
            float e = __expf(lgr[pp] - a1);
            float ge = (lgr[pp] >= thresh) ? e : 0.f;   // ref semantics: >=
            garr[pp] = ge; den += ge;
        }
        float inv = 1.f / den;
        float4* grow = (float4*)&gates_g[((size_t)h * NTOK + t0 + t) * 32];
#pragma unroll
        for (int c = 0; c < 8; ++c)
            grow[c] = make_float4(garr[4 * c] * inv, garr[4 * c + 1] * inv,
                                  garr[4 * c + 2] * inv, garr[4 * c + 3] * inv);
    }
}

// ---------------------------------------------------------------------------
// Kernel 2b (attn_v5): scores MFMA + r-softmax/gate (wf) + heads MFMA.
// Block = 64 tokens x 1 head. Gates staged from global. Heads phase: each
// wave computes ALL 64 d for its own 16 tokens (nt = w), so every (t,h)
// 128B hb line is written by one wave -> no partial-sector write amp.
// MFMA accumulation order per acc register identical to R4 (bit-identical).
// ---------------------------------------------------------------------------
__global__ __launch_bounds__(256, 3) void attn_v5(const float* __restrict__ x,
                                                  const __hip_bfloat16* __restrict__ kfrag,
                                                  const __hip_bfloat16* __restrict__ vfrag,
                                                  const float* __restrict__ gates_g,
                                                  __hip_bfloat16* __restrict__ hb) {
    __shared__ __align__(16) float gates[64][36];
    __shared__ __align__(16) short wf[16384];     // 32 KB w B-frags

    const int lane = threadIdx.x & 63;
    const int w = threadIdx.x >> 6;
    const int l15 = lane & 15, l4 = lane >> 4;
    const int t0 = blockIdx.x * 64;
    const int h = blockIdx.y;

    // ---- stage gates tile [64 t x 32 p] from global into LDS ----
    {
        int j0 = threadIdx.x * 2;
#pragma unroll
        for (int u = 0; u < 2; ++u) {
            int j = j0 + u;
            int t = j >> 3, c = j & 7;
            float4 g4 = *(const float4*)&gates_g[((size_t)h * NTOK + t0 + t) * 32 + c * 4];
            *(float4*)&gates[t][c * 4] = g4;
        }
    }

    // ---- scores GEMM: S^T[pr][t]; A = kfrag (global), B = x (global) ----
    short8 xb[4][2];
#pragma unroll
    for (int nt = 0; nt < 4; ++nt)
#pragma unroll
        for (int kb = 0; kb < 2; ++kb) {
            const float* bp = x + (size_t)(t0 + nt * 16 + l15) * DM + h * 64 + kb * 32 + l4 * 8;
            float4 lo = *(const float4*)bp;
            float4 hi = *(const float4*)(bp + 4);
            xb[nt][kb] = pk8(lo, hi);
        }
    short8 ka[4][2];
#pragma unroll
    for (int mi = 0; mi < 4; ++mi)
#pragma unroll
        for (int kb = 0; kb < 2; ++kb)
            ka[mi][kb] = *(const short8*)((const short*)kfrag +
                          ((size_t)(h * 32 + (w * 4 + mi) * 2 + kb) * 512 + lane * 8));

    floatx4 acc[4][4] = {};
#pragma unroll
    for (int kb = 0; kb < 2; ++kb)
#pragma unroll
        for (int mi = 0; mi < 4; ++mi)
#pragma unroll
            for (int nt = 0; nt < 4; ++nt)
                acc[mi][nt] = __builtin_amdgcn_mfma_f32_16x16x32_bf16(ka[mi][kb], xb[nt][kb], acc[mi][nt], 0, 0, 0);

    __syncthreads();   // gates staged; scores done (acc in regs)

    // ---- r-softmax + gate -> w B-frags in LDS ----
#pragma unroll
    for (int mi = 0; mi < 4; ++mi) {
        const int mt = w * 4 + mi;
        const int pidx = mt * 2 + (l4 >> 1);
#pragma unroll
        for (int nt = 0; nt < 4; ++nt) {
            float g = gates[nt * 16 + l15][pidx];
            float s0 = acc[mi][nt][0] * 0.125f;
            float s1 = acc[mi][nt][1] * 0.125f;
            float s2 = acc[mi][nt][2] * 0.125f;
            float s3 = acc[mi][nt][3] * 0.125f;
            float mx = fmaxf(fmaxf(s0, s1), fmaxf(s2, s3));
            mx = fmaxf(mx, __shfl_xor(mx, 16));
            float e0 = __expf(s0 - mx), e1 = __expf(s1 - mx);
            float e2 = __expf(s2 - mx), e3 = __expf(s3 - mx);
            float loc = (e0 + e1) + (e2 + e3);
            float se = loc + __shfl_xor(loc, 16);
            float ws = g / se;
            int2 pk;
            pk.x = pk2(e0 * ws, e1 * ws);
            pk.y = pk2(e2 * ws, e3 * ws);
            int off = (((mt & 1) * 2 + (l4 >> 1)) * 16 + l15) * 8 + (l4 & 1) * 4;
            *(int2*)&wf[(nt * 8 + (mt >> 1)) * 512 + off] = pk;
        }
    }
    __syncthreads();

    // ---- heads GEMM: wave w owns tokens nt=w, computes all d (mt 0..3) ----
    floatx4 h4[4] = {};
#pragma unroll
    for (int kb = 0; kb < 8; ++kb) {
        short8 wb = *(const short8*)&wf[(w * 8 + kb) * 512 + lane * 8];
#pragma unroll
        for (int mt = 0; mt < 4; ++mt) {
            short8 va = *(const short8*)((const short*)vfrag +
                          ((size_t)(h * 32 + mt * 8 + kb) * 512 + lane * 8));
            h4[mt] = __builtin_amdgcn_mfma_f32_16x16x32_bf16(va, wb, h4[mt], 0, 0, 0);
        }
    }
    // store: token t = t0 + w*16 + l15 gets full 128B line from this wave
    {
        const int t = t0 + w * 16 + l15;
        short* dstbase = (short*)hb + (size_t)t * DM + h * 64;
#pragma unroll
        for (int mt = 0; mt < 4; ++mt) {
            int2 pk;
            pk.x = pk2(h4[mt][0], h4[mt][1]);
            pk.y = pk2(h4[mt][2], h4[mt][3]);
            *(int2*)(dstbase + mt * 16 + l4 * 4) = pk;
        }
    }
}

// ---------------------------------------------------------------------------
// Kernel 3 (v2): m97-style GEMM (unchanged from R4).
// ---------------------------------------------------------------------------
__global__ __launch_bounds__(256) void gemm_v2(const __hip_bfloat16* __restrict__ Abf,
                                               const __hip_bfloat16* __restrict__ Bsw,
                                               const float* __restrict__ bias,
                                               float* __restrict__ C) {
    __shared__ __align__(16) short As[4096];      // 128 rows x 32 k = 8 KB
    const int lane = threadIdx.x & 63;
    const int wave = threadIdx.x >> 6;
    const int wm = wave >> 1, wn = wave & 1;
    const int bm0 = blockIdx.y * 128;
    const int bn0 = blockIdx.x * 128;
    const int l15 = lane & 15, l4 = lane >> 4;

    const short* Ap = (const short*)Abf;
    const short* Bp = (const short*)Bsw;

    const int c0 = (wave * 2 + 0) * 64 + lane;
    const int c1 = (wave * 2 + 1) * 64 + lane;
    const short* g0 = Ap + (size_t)(bm0 + (c0 >> 2)) * KK + (c0 & 3) * 8;
    const short* g1 = Ap + (size_t)(bm0 + (c1 >> 2)) * KK + (c1 & 3) * 8;
    short* l0 = &As[(wave * 2 + 0) * 512];
    short* l1 = &As[(wave * 2 + 1) * 512];

    int boff[4];
#pragma unroll
    for (int nt = 0; nt < 4; ++nt)
        boff[nt] = (((bn0 >> 4) + wn * 4 + nt) * 32) * 512 + lane * 8;

    int aoff[4];
#pragma unroll
    for (int mt = 0; mt < 4; ++mt)
        aoff[mt] = ((wm * 64 + mt * 16 + l15) * 4 + l4) * 8;

    floatx4 acc[4][4] = {};

    for (int kb = 0; kb < 32; ++kb) {
        __syncthreads();
        short8 b[4];
#pragma unroll
        for (int nt = 0; nt < 4; ++nt)
            b[nt] = *(const short8*)(Bp + boff[nt] + kb * 512);
        __builtin_amdgcn_global_load_lds(
            (const __attribute__((address_space(1))) unsigned int*)(g0 + kb * 32),
            (__attribute__((address_space(3))) unsigned int*)l0, 16, 0, 0);
        __builtin_amdgcn_global_load_lds(
            (const __attribute__((address_space(1))) unsigned int*)(g1 + kb * 32),
            (__attribute__((address_space(3))) unsigned int*)l1, 16, 0, 0);
        __syncthreads();
        short8 a[4];
#pragma unroll
        for (int mt = 0; mt < 4; ++mt)
            a[mt] = *(const short8*)&As[aoff[mt]];
#pragma unroll
        for (int mt = 0; mt < 4; ++mt)
#pragma unroll
            for (int nt = 0; nt < 4; ++nt)
                acc[mt][nt] = __builtin_amdgcn_mfma_f32_16x16x32_bf16(a[mt], b[nt], acc[mt][nt], 0, 0, 0);
    }

#pragma unroll
    for (int nt = 0; nt < 4; ++nt) {
        const int col = bn0 + wn * 64 + nt * 16 + l15;
        const float bv = bias[col];
#pragma unroll
        for (int mt = 0; mt < 4; ++mt) {
            const int row0 = bm0 + wm * 64 + mt * 16 + l4 * 4;
#pragma unroll
            for (int i = 0; i < 4; ++i)
                C[(size_t)(row0 + i) * NN + col] = acc[mt][nt][i] + bv;
        }
    }
}

// ---------------------------------------------------------------------------
extern "C" void kernel_launch(void* const* d_in, const int* in_sizes, int n_in,
                              void* d_out, int out_size, void* d_ws, size_t ws_size,
                              hipStream_t stream) {
    const float* x   = (const float*)d_in[0];
    const float* Kst = (const float*)d_in[1];
    const float* Vst = (const float*)d_in[2];
    const float* Wr  = (const float*)d_in[3];
    const float* Wo  = (const float*)d_in[4];
    const float* bo  = (const float*)d_in[5];
    const int*   kp  = (const int*)d_in[6];
    float* out = (float*)d_out;

    __hip_bfloat16* hb    = (__hip_bfloat16*)d_ws;             // 16M bf16 = 32 MiB
    __hip_bfloat16* wsw   = hb + (size_t)MM * KK;              // 1M bf16  = 2 MiB
    __hip_bfloat16* kfrag = wsw + (size_t)KK * NN;             // 256K bf16
    __hip_bfloat16* vfrag = kfrag + 16 * 32 * 512;             // 256K bf16
    // gates live in d_out (32 MB of 64 MB): written by router, consumed by
    // attn_v5, then d_out fully overwritten by gemm_v2.
    float* gates_g = out;

    convert_w<<<dim3(512), 256, 0, stream>>>(Wo, wsw);
    convert_kv<<<dim3(256), 256, 0, stream>>>(Kst, Vst, kfrag, vfrag);
    router<<<dim3(NTOK / 64, HH), 256, 0, stream>>>(x, Wr, kp, gates_g);
    attn_v5<<<dim3(NTOK / 64, HH), 256, 0, stream>>>(x, kfrag, vfrag, gates_g, hb);
    gemm_v2<<<dim3(NN / 128, MM / 128), 256, 0, stream>>>(hb, wsw, bo, out);
}